// Round 1
// baseline (334.336 us; speedup 1.0000x reference)
//
#include <hip/hip_runtime.h>
#include <stdint.h>

typedef __attribute__((ext_vector_type(8))) short bh8;       // 8 x bf16 (4 VGPR)
typedef __attribute__((ext_vector_type(4))) float f32x4;
typedef __attribute__((ext_vector_type(4))) unsigned short u16x4;
typedef __attribute__((ext_vector_type(8))) unsigned short u16x8;

#define DEVI static __device__ __forceinline__

constexpr int B_ = 2, S_ = 2048, D_ = 1024, H_ = 16, E_ = 64;

// workspace layout (elements of ushort/bf16)
constexpr size_t OFF_XB  = 0;                              // x as bf16 [B*S, D]
constexpr size_t OFF_WQT = OFF_XB  + (size_t)B_*S_*D_;     // WqT [H, E, D]
constexpr size_t OFF_WKT = OFF_WQT + (size_t)H_*E_*D_;
constexpr size_t OFF_WVT = OFF_WKT + (size_t)H_*E_*D_;
constexpr size_t OFF_WOT = OFF_WVT + (size_t)H_*E_*D_;     // WoT [D, D]
constexpr size_t OFF_Q   = OFF_WOT + (size_t)D_*D_;        // [B*H, S, E]  (pre-scaled by 1/8)
constexpr size_t OFF_K   = OFF_Q   + (size_t)B_*H_*S_*E_;  // [B*H, S, E]
constexpr size_t OFF_VT  = OFF_K   + (size_t)B_*H_*S_*E_;  // [B*H, E, S]
constexpr size_t OFF_O   = OFF_VT  + (size_t)B_*H_*S_*E_;  // attn out concat [B*S, D]
// total = 25165824 ushorts = 48 MiB

DEVI unsigned short f2bf(float f) {
    union { float f; unsigned u; } v; v.f = f;
    unsigned u = v.u;
    return (unsigned short)((u + 0x7fffu + ((u >> 16) & 1u)) >> 16);
}

DEVI void gload16(const void* g, void* l) {
    __builtin_amdgcn_global_load_lds(
        (const __attribute__((address_space(1))) unsigned int*)g,
        (__attribute__((address_space(3))) unsigned int*)l, 16, 0, 0);
}

DEVI f32x4 mfma16(bh8 a, bh8 b, f32x4 c) {
    return __builtin_amdgcn_mfma_f32_16x16x32_bf16(a, b, c, 0, 0, 0);
}

DEVI float redmax16(float v) {
    v = fmaxf(v, __shfl_xor(v, 1, 64));
    v = fmaxf(v, __shfl_xor(v, 2, 64));
    v = fmaxf(v, __shfl_xor(v, 4, 64));
    v = fmaxf(v, __shfl_xor(v, 8, 64));
    return v;
}
DEVI float redsum16(float v) {
    v += __shfl_xor(v, 1, 64);
    v += __shfl_xor(v, 2, 64);
    v += __shfl_xor(v, 4, 64);
    v += __shfl_xor(v, 8, 64);
    return v;
}

// ---------------- prep: x -> bf16 ----------------
__global__ __launch_bounds__(256) void k_convert_x(const float* __restrict__ x,
                                                   unsigned short* __restrict__ ws) {
    const int i = blockIdx.x * 256 + threadIdx.x;   // one float4 each; n4 = 1048576
    const float4 v = ((const float4*)x)[i];
    u16x4 o = { f2bf(v.x), f2bf(v.y), f2bf(v.z), f2bf(v.w) };
    *(u16x4*)(ws + OFF_XB + (size_t)i * 4) = o;
}

// ---------------- prep: weights -> bf16, transposed ----------------
// z<3: Wq/Wk/Wv [H,1024,64] -> WT [H,64,1024];  z==3: Wo [1024,1024] -> [1024,1024]^T
__global__ __launch_bounds__(256) void k_transpose_w(const float* __restrict__ Wq,
                                                     const float* __restrict__ Wk,
                                                     const float* __restrict__ Wv,
                                                     const float* __restrict__ Wo,
                                                     unsigned short* __restrict__ ws) {
    const int xi = blockIdx.x;   // 0..255
    const int z  = blockIdx.y;   // 0..3
    const int t  = threadIdx.x;
    __shared__ __align__(16) unsigned short tile[64][72];

    const float* src; unsigned short* dst;
    int inCols, inBase, outBase;
    if (z < 3) {
        src = (z == 0) ? Wq : (z == 1) ? Wk : Wv;
        dst = ws + ((z == 0) ? OFF_WQT : (z == 1) ? OFF_WKT : OFF_WVT);
        inCols = 64;
        inBase = xi * 64 * 64;                  // rows xi*64.. of flat [16384,64]
        const int h = xi >> 4, dt = xi & 15;
        outBase = h * 65536 + dt * 64;          // + j*1024 + i
    } else {
        src = Wo; dst = ws + OFF_WOT;
        inCols = 1024;
        const int et = xi >> 4, dt = xi & 15;
        inBase  = (dt * 64) * 1024 + et * 64;
        outBase = (et * 64) * 1024 + dt * 64;
    }
#pragma unroll
    for (int v = 0; v < 4; ++v) {
        const int flat = v * 256 + t;
        const int i = flat >> 4, j4 = (flat & 15) * 4;
        const float4 val = *(const float4*)(src + inBase + i * inCols + j4);
        tile[i][j4 + 0] = f2bf(val.x);
        tile[i][j4 + 1] = f2bf(val.y);
        tile[i][j4 + 2] = f2bf(val.z);
        tile[i][j4 + 3] = f2bf(val.w);
    }
    __syncthreads();
    const int j = t >> 2, iseg = (t & 3) * 16;
    u16x8 p0, p1;
#pragma unroll
    for (int u = 0; u < 8; ++u) p0[u] = tile[iseg + u][j];
#pragma unroll
    for (int u = 0; u < 8; ++u) p1[u] = tile[iseg + 8 + u][j];
    *(u16x8*)(dst + outBase + (size_t)j * 1024 + iseg)     = p0;
    *(u16x8*)(dst + outBase + (size_t)j * 1024 + iseg + 8) = p1;
}

// ---------------- shared GEMM mainloop: C(128x64) = A(128x1024) * B^T(64x1024)^T ----------------
// LDS layout is MFMA-fragment-order: each 1KB block = one 16x32 fragment, lane-linear
// -> global_load_lds dest is linear AND ds_read_b128 is conflict-free.
DEVI void gemm_tile_128x64(const unsigned short* __restrict__ A,   // block row0, ld=1024
                           const unsigned short* __restrict__ Bw,  // B^T col-panel, ld=1024
                           unsigned short* ldsA, unsigned short* ldsB,
                           f32x4 acc[2][4]) {
    const int lane = threadIdx.x & 63;
    const int w    = threadIdx.x >> 6;
    const int lr = lane & 15, lg = lane >> 4;
    const unsigned short* a0 = A  + (size_t)((w * 2 + 0) * 16 + lr) * D_ + lg * 8;
    const unsigned short* a1 = A  + (size_t)((w * 2 + 1) * 16 + lr) * D_ + lg * 8;
    const unsigned short* b0 = Bw + (size_t)(w * 16 + lr) * D_ + lg * 8;
    unsigned short* dA0 = ldsA + (w * 2 + 0) * 512;
    unsigned short* dA1 = ldsA + (w * 2 + 1) * 512;
    unsigned short* dB0 = ldsB + w * 512;
    for (int ks = 0; ks < 32; ++ks) {
        gload16(a0 + ks * 32, dA0);
        gload16(a1 + ks * 32, dA1);
        gload16(b0 + ks * 32, dB0);
        __syncthreads();
        bh8 af0 = *(const bh8*)(ldsA + (w * 2 + 0) * 512 + lane * 8);
        bh8 af1 = *(const bh8*)(ldsA + (w * 2 + 1) * 512 + lane * 8);
#pragma unroll
        for (int nt = 0; nt < 4; ++nt) {
            bh8 bf = *(const bh8*)(ldsB + nt * 512 + lane * 8);
            acc[0][nt] = mfma16(af0, bf, acc[0][nt]);
            acc[1][nt] = mfma16(af1, bf, acc[1][nt]);
        }
        __syncthreads();
    }
}

// ---------------- QKV projection ----------------
__global__ __launch_bounds__(256) void k_qkv(unsigned short* __restrict__ ws,
                                             const float* __restrict__ bq,
                                             const float* __restrict__ bk,
                                             const float* __restrict__ bv) {
    const int stile = blockIdx.x;   // 0..31 (rows of [4096,1024])
    const int h     = blockIdx.y;   // 0..15
    const int mat   = blockIdx.z;   // 0=Q 1=K 2=V
    const int row0  = stile * 128;
    const int b     = row0 >> 11;
    const int bh    = b * H_ + h;
    const unsigned short* A  = ws + OFF_XB + (size_t)row0 * D_;
    const unsigned short* Bw = ws + ((mat == 0) ? OFF_WQT : (mat == 1) ? OFF_WKT : OFF_WVT)
                                  + (size_t)h * E_ * D_;
    const float* bias = ((mat == 0) ? bq : (mat == 1) ? bk : bv) + h * E_;

    __shared__ __align__(16) unsigned short lds[12 * 512];
    f32x4 acc[2][4];
#pragma unroll
    for (int i = 0; i < 2; ++i)
#pragma unroll
        for (int j = 0; j < 4; ++j) acc[i][j] = (f32x4){0.f, 0.f, 0.f, 0.f};

    gemm_tile_128x64(A, Bw, lds, lds + 8 * 512, acc);

    const int lane = threadIdx.x & 63, w = threadIdx.x >> 6;
    const int lr = lane & 15, lg = lane >> 4;
    const int srow0 = row0 + w * 32;          // global row
    const int sl0   = srow0 & (S_ - 1);       // s within batch
#pragma unroll
    for (int mt = 0; mt < 2; ++mt) {
#pragma unroll
        for (int nt = 0; nt < 4; ++nt) {
            const int e = nt * 16 + lr;
            const float bia = bias[e];
            if (mat == 2) {
                u16x4 pk;
#pragma unroll
                for (int r = 0; r < 4; ++r) pk[r] = f2bf(acc[mt][nt][r] + bia);
                const int sl = sl0 + mt * 16 + lg * 4;
                *(u16x4*)(ws + OFF_VT + ((size_t)(bh * E_ + e)) * S_ + sl) = pk;
            } else {
#pragma unroll
                for (int r = 0; r < 4; ++r) {
                    float v = acc[mt][nt][r] + bia;
                    const int sl = sl0 + mt * 16 + lg * 4 + r;
                    if (mat == 0)
                        ws[OFF_Q + ((size_t)bh * S_ + sl) * E_ + e] = f2bf(v * 0.125f);
                    else
                        ws[OFF_K + ((size_t)bh * S_ + sl) * E_ + e] = f2bf(v);
                }
            }
        }
    }
}

// ---------------- flash attention (causal) ----------------
__global__ __launch_bounds__(256) void k_attn(unsigned short* __restrict__ ws) {
    const int qt = blockIdx.x;   // 0..15  (128 q rows each)
    const int bh = blockIdx.y;   // 0..31
    const int lane = threadIdx.x & 63, w = threadIdx.x >> 6;
    const int lr = lane & 15, lg = lane >> 4;
    const unsigned short* Qp = ws + OFF_Q  + (size_t)bh * S_ * E_;
    const unsigned short* Kp = ws + OFF_K  + (size_t)bh * S_ * E_;
    const unsigned short* Vp = ws + OFF_VT + (size_t)bh * E_ * S_;
    __shared__ __align__(16) unsigned short ldsK[8 * 512];
    __shared__ __align__(16) unsigned short ldsV[8 * 512];
    __shared__ __align__(16) unsigned short ldsP[4 * 4 * 512];

    const int qbase = qt * 128 + w * 32;   // s index of this wave's 32 rows
    bh8 qf[2][2];
#pragma unroll
    for (int mt = 0; mt < 2; ++mt)
#pragma unroll
        for (int kg = 0; kg < 2; ++kg)
            qf[mt][kg] = *(const bh8*)(Qp + (size_t)(qbase + mt * 16 + lr) * E_ + kg * 32 + lg * 8);

    f32x4 o[2][4];
    float m[2][4], l[2][4];
#pragma unroll
    for (int mt = 0; mt < 2; ++mt)
#pragma unroll
        for (int i = 0; i < 4; ++i) {
            o[mt][i] = (f32x4){0.f, 0.f, 0.f, 0.f};
            m[mt][i] = -3.0e38f; l[mt][i] = 0.f;
        }

    unsigned short* Pw = ldsP + w * 2048;
    const int nkt = (qt + 1) * 2;
    for (int kt = 0; kt < nkt; ++kt) {
        const int sk0 = kt * 64;
        // stage K (B-frag order for QK^T) and V^T (B-frag order for PV): 4 calls/wave
#pragma unroll
        for (int u = 0; u < 2; ++u) {
            const int blk = w * 2 + u;
            const int ct = blk >> 1, kg = blk & 1;     // K: 16 s_k cols x 32 e
            gload16(Kp + (size_t)(sk0 + ct * 16 + lr) * E_ + kg * 32 + lg * 8,
                    (unsigned short*)ldsK + blk * 512);
            const int et = ct, skg = kg;               // V: 16 e cols x 32 s_k
            gload16(Vp + (size_t)(et * 16 + lr) * S_ + sk0 + skg * 32 + lg * 8,
                    (unsigned short*)ldsV + blk * 512);
        }
        __syncthreads();

        // S = Q K^T  (Q pre-scaled)
        f32x4 sc[2][4];
#pragma unroll
        for (int mt = 0; mt < 2; ++mt)
#pragma unroll
            for (int ct = 0; ct < 4; ++ct) sc[mt][ct] = (f32x4){0.f, 0.f, 0.f, 0.f};
#pragma unroll
        for (int ct = 0; ct < 4; ++ct)
#pragma unroll
            for (int kg = 0; kg < 2; ++kg) {
                bh8 kf = *(const bh8*)(ldsK + (ct * 2 + kg) * 512 + lane * 8);
                sc[0][ct] = mfma16(qf[0][kg], kf, sc[0][ct]);
                sc[1][ct] = mfma16(qf[1][kg], kf, sc[1][ct]);
            }
        // causal mask
#pragma unroll
        for (int mt = 0; mt < 2; ++mt)
#pragma unroll
            for (int ct = 0; ct < 4; ++ct) {
                const int skc = sk0 + ct * 16 + lr;
#pragma unroll
                for (int r = 0; r < 4; ++r) {
                    const int sq = qbase + mt * 16 + lg * 4 + r;
                    if (skc > sq) sc[mt][ct][r] = -3.0e38f;
                }
            }
        // online softmax: row max, rescale o/l
#pragma unroll
        for (int mt = 0; mt < 2; ++mt)
#pragma unroll
            for (int r = 0; r < 4; ++r) {
                float mx = fmaxf(fmaxf(sc[mt][0][r], sc[mt][1][r]),
                                 fmaxf(sc[mt][2][r], sc[mt][3][r]));
                mx = redmax16(mx);
                const float mn = fmaxf(m[mt][r], mx);
                const float sf = exp2f((m[mt][r] - mn) * 1.44269504f);
                m[mt][r] = mn;
                l[mt][r] *= sf;
#pragma unroll
                for (int et = 0; et < 4; ++et) o[mt][et][r] *= sf;
            }
        // P = exp(S-m), row sums
        float rs[2][4];
#pragma unroll
        for (int mt = 0; mt < 2; ++mt)
#pragma unroll
            for (int r = 0; r < 4; ++r) rs[mt][r] = 0.f;
#pragma unroll
        for (int mt = 0; mt < 2; ++mt)
#pragma unroll
            for (int ct = 0; ct < 4; ++ct)
#pragma unroll
                for (int r = 0; r < 4; ++r) {
                    float p = exp2f((sc[mt][ct][r] - m[mt][r]) * 1.44269504f);
                    sc[mt][ct][r] = p;
                    rs[mt][r] += p;
                }
#pragma unroll
        for (int mt = 0; mt < 2; ++mt)
#pragma unroll
            for (int r = 0; r < 4; ++r) l[mt][r] += redsum16(rs[mt][r]);
        // write P (bf16) into per-wave LDS in A-frag order
#pragma unroll
        for (int mt = 0; mt < 2; ++mt)
#pragma unroll
            for (int ct = 0; ct < 4; ++ct) {
                const int blk = mt * 2 + (ct >> 1);
                const int lanep = ((ct & 1) * 2 + (lr >> 3)) * 16;
                const int elem = lr & 7;
#pragma unroll
                for (int r = 0; r < 4; ++r)
                    Pw[blk * 512 + (lanep + lg * 4 + r) * 8 + elem] = f2bf(sc[mt][ct][r]);
            }
        // O += P V  (wave-local LDS; compiler orders via lgkmcnt, no barrier needed)
#pragma unroll
        for (int skg = 0; skg < 2; ++skg) {
            bh8 pf0 = *(const bh8*)(Pw + (0 * 2 + skg) * 512 + lane * 8);
            bh8 pf1 = *(const bh8*)(Pw + (1 * 2 + skg) * 512 + lane * 8);
#pragma unroll
            for (int et = 0; et < 4; ++et) {
                bh8 vf = *(const bh8*)(ldsV + (et * 2 + skg) * 512 + lane * 8);
                o[0][et] = mfma16(pf0, vf, o[0][et]);
                o[1][et] = mfma16(pf1, vf, o[1][et]);
            }
        }
        __syncthreads();   // before restaging K/V
    }
    // epilogue: O/l -> concat layout [B,S,H*64]
    const int b = bh >> 4, hh = bh & 15;
#pragma unroll
    for (int mt = 0; mt < 2; ++mt)
#pragma unroll
        for (int r = 0; r < 4; ++r) {
            const float inv = 1.0f / l[mt][r];
            const int s = qbase + mt * 16 + lg * 4 + r;
#pragma unroll
            for (int et = 0; et < 4; ++et)
                ws[OFF_O + ((size_t)(b * S_ + s)) * D_ + hh * E_ + et * 16 + lr] =
                    f2bf(o[mt][et][r] * inv);
        }
}

// ---------------- output projection ----------------
__global__ __launch_bounds__(256) void k_oproj(const unsigned short* __restrict__ ws,
                                               const float* __restrict__ bo,
                                               float* __restrict__ out) {
    const int stile = blockIdx.x;   // 0..31
    const int ntile = blockIdx.y;   // 0..15
    const unsigned short* A  = ws + OFF_O   + (size_t)stile * 128 * D_;
    const unsigned short* Bw = ws + OFF_WOT + (size_t)ntile * 64 * D_;
    __shared__ __align__(16) unsigned short lds[12 * 512];
    f32x4 acc[2][4];
#pragma unroll
    for (int i = 0; i < 2; ++i)
#pragma unroll
        for (int j = 0; j < 4; ++j) acc[i][j] = (f32x4){0.f, 0.f, 0.f, 0.f};

    gemm_tile_128x64(A, Bw, (unsigned short*)lds, (unsigned short*)lds + 8 * 512, acc);

    const int lane = threadIdx.x & 63, w = threadIdx.x >> 6;
    const int lr = lane & 15, lg = lane >> 4;
    const int r0 = stile * 128 + w * 32;
#pragma unroll
    for (int mt = 0; mt < 2; ++mt)
#pragma unroll
        for (int nt = 0; nt < 4; ++nt) {
            const int e = ntile * 64 + nt * 16 + lr;
            const float bia = bo[e];
#pragma unroll
            for (int r = 0; r < 4; ++r)
                out[(size_t)(r0 + mt * 16 + lg * 4 + r) * D_ + e] = acc[mt][nt][r] + bia;
        }
}

extern "C" void kernel_launch(void* const* d_in, const int* in_sizes, int n_in,
                              void* d_out, int out_size, void* d_ws, size_t ws_size,
                              hipStream_t stream) {
    const float* x  = (const float*)d_in[0];
    const float* Wq = (const float*)d_in[1];
    const float* bq = (const float*)d_in[2];
    const float* Wk = (const float*)d_in[3];
    const float* bk = (const float*)d_in[4];
    const float* Wv = (const float*)d_in[5];
    const float* bv = (const float*)d_in[6];
    const float* Wo = (const float*)d_in[7];
    const float* bo = (const float*)d_in[8];
    float* out = (float*)d_out;
    unsigned short* ws = (unsigned short*)d_ws;

    k_convert_x<<<dim3((B_ * S_ * D_) / 4 / 256), 256, 0, stream>>>(x, ws);
    k_transpose_w<<<dim3(256, 4), 256, 0, stream>>>(Wq, Wk, Wv, Wo, ws);
    k_qkv<<<dim3(32, 16, 3), 256, 0, stream>>>(ws, bq, bk, bv);
    k_attn<<<dim3(16, 32), 256, 0, stream>>>(ws);
    k_oproj<<<dim3(32, 16), 256, 0, stream>>>(ws, bo, out);
}

// Round 2
// 226.155 us; speedup vs baseline: 1.4784x; 1.4784x over previous
//
#include <hip/hip_runtime.h>
#include <stdint.h>

typedef __attribute__((ext_vector_type(8))) short bh8;       // 8 x bf16 (4 VGPR)
typedef __attribute__((ext_vector_type(4))) float f32x4;
typedef __attribute__((ext_vector_type(4))) unsigned short u16x4;
typedef __attribute__((ext_vector_type(8))) unsigned short u16x8;

#define DEVI static __device__ __forceinline__

constexpr int B_ = 2, S_ = 2048, D_ = 1024, H_ = 16, E_ = 64;

// workspace layout (elements of ushort/bf16)
constexpr size_t OFF_XB  = 0;                              // x as bf16 [B*S, D]
constexpr size_t OFF_WQT = OFF_XB  + (size_t)B_*S_*D_;     // WqT [H, E, D]
constexpr size_t OFF_WKT = OFF_WQT + (size_t)H_*E_*D_;
constexpr size_t OFF_WVT = OFF_WKT + (size_t)H_*E_*D_;
constexpr size_t OFF_WOT = OFF_WVT + (size_t)H_*E_*D_;     // WoT [D, D]
constexpr size_t OFF_Q   = OFF_WOT + (size_t)D_*D_;        // [B*H, S, E]  (pre-scaled by 0.125*log2e)
constexpr size_t OFF_K   = OFF_Q   + (size_t)B_*H_*S_*E_;  // [B*H, S, E]
constexpr size_t OFF_VT  = OFF_K   + (size_t)B_*H_*S_*E_;  // [B*H, E, S]
constexpr size_t OFF_O   = OFF_VT  + (size_t)B_*H_*S_*E_;  // attn out concat [B*S, D]

DEVI unsigned short f2bf(float f) {
    union { float f; unsigned u; } v; v.f = f;
    unsigned u = v.u;
    return (unsigned short)((u + 0x7fffu + ((u >> 16) & 1u)) >> 16);
}

DEVI void gload16(const void* g, void* l) {
    __builtin_amdgcn_global_load_lds(
        (const __attribute__((address_space(1))) unsigned int*)g,
        (__attribute__((address_space(3))) unsigned int*)l, 16, 0, 0);
}

DEVI f32x4 mfma16(bh8 a, bh8 b, f32x4 c) {
    return __builtin_amdgcn_mfma_f32_16x16x32_bf16(a, b, c, 0, 0, 0);
}

DEVI float redmax16(float v) {
    v = fmaxf(v, __shfl_xor(v, 1, 64));
    v = fmaxf(v, __shfl_xor(v, 2, 64));
    v = fmaxf(v, __shfl_xor(v, 4, 64));
    v = fmaxf(v, __shfl_xor(v, 8, 64));
    return v;
}
DEVI float redsum16(float v) {
    v += __shfl_xor(v, 1, 64);
    v += __shfl_xor(v, 2, 64);
    v += __shfl_xor(v, 4, 64);
    v += __shfl_xor(v, 8, 64);
    return v;
}

// ---------------- prep: x -> bf16 ----------------
__global__ __launch_bounds__(256) void k_convert_x(const float* __restrict__ x,
                                                   unsigned short* __restrict__ ws) {
    const int i = blockIdx.x * 256 + threadIdx.x;   // one float4 each; n4 = 1048576
    const float4 v = ((const float4*)x)[i];
    u16x4 o = { f2bf(v.x), f2bf(v.y), f2bf(v.z), f2bf(v.w) };
    *(u16x4*)(ws + OFF_XB + (size_t)i * 4) = o;
}

// ---------------- prep: weights -> bf16, transposed ----------------
__global__ __launch_bounds__(256) void k_transpose_w(const float* __restrict__ Wq,
                                                     const float* __restrict__ Wk,
                                                     const float* __restrict__ Wv,
                                                     const float* __restrict__ Wo,
                                                     unsigned short* __restrict__ ws) {
    const int xi = blockIdx.x;   // 0..255
    const int z  = blockIdx.y;   // 0..3
    const int t  = threadIdx.x;
    __shared__ __align__(16) unsigned short tile[64][72];

    const float* src; unsigned short* dst;
    int inCols, inBase, outBase;
    if (z < 3) {
        src = (z == 0) ? Wq : (z == 1) ? Wk : Wv;
        dst = ws + ((z == 0) ? OFF_WQT : (z == 1) ? OFF_WKT : OFF_WVT);
        inCols = 64;
        inBase = xi * 64 * 64;
        const int h = xi >> 4, dt = xi & 15;
        outBase = h * 65536 + dt * 64;
    } else {
        src = Wo; dst = ws + OFF_WOT;
        inCols = 1024;
        const int et = xi >> 4, dt = xi & 15;
        inBase  = (dt * 64) * 1024 + et * 64;
        outBase = (et * 64) * 1024 + dt * 64;
    }
#pragma unroll
    for (int v = 0; v < 4; ++v) {
        const int flat = v * 256 + t;
        const int i = flat >> 4, j4 = (flat & 15) * 4;
        const float4 val = *(const float4*)(src + inBase + i * inCols + j4);
        tile[i][j4 + 0] = f2bf(val.x);
        tile[i][j4 + 1] = f2bf(val.y);
        tile[i][j4 + 2] = f2bf(val.z);
        tile[i][j4 + 3] = f2bf(val.w);
    }
    __syncthreads();
    const int j = t >> 2, iseg = (t & 3) * 16;
    u16x8 p0, p1;
#pragma unroll
    for (int u = 0; u < 8; ++u) p0[u] = tile[iseg + u][j];
#pragma unroll
    for (int u = 0; u < 8; ++u) p1[u] = tile[iseg + 8 + u][j];
    *(u16x8*)(dst + outBase + (size_t)j * 1024 + iseg)     = p0;
    *(u16x8*)(dst + outBase + (size_t)j * 1024 + iseg + 8) = p1;
}

// ---------------- shared GEMM mainloop: C(128x64) = A(128x1024) * B^T(64x1024)^T ----------------
DEVI void gemm_tile_128x64(const unsigned short* __restrict__ A,
                           const unsigned short* __restrict__ Bw,
                           unsigned short* ldsA, unsigned short* ldsB,
                           f32x4 acc[2][4]) {
    const int lane = threadIdx.x & 63;
    const int w    = threadIdx.x >> 6;
    const int lr = lane & 15, lg = lane >> 4;
    const unsigned short* a0 = A  + (size_t)((w * 2 + 0) * 16 + lr) * D_ + lg * 8;
    const unsigned short* a1 = A  + (size_t)((w * 2 + 1) * 16 + lr) * D_ + lg * 8;
    const unsigned short* b0 = Bw + (size_t)(w * 16 + lr) * D_ + lg * 8;
    unsigned short* dA0 = ldsA + (w * 2 + 0) * 512;
    unsigned short* dA1 = ldsA + (w * 2 + 1) * 512;
    unsigned short* dB0 = ldsB + w * 512;
    for (int ks = 0; ks < 32; ++ks) {
        gload16(a0 + ks * 32, dA0);
        gload16(a1 + ks * 32, dA1);
        gload16(b0 + ks * 32, dB0);
        __syncthreads();
        bh8 af0 = *(const bh8*)(ldsA + (w * 2 + 0) * 512 + lane * 8);
        bh8 af1 = *(const bh8*)(ldsA + (w * 2 + 1) * 512 + lane * 8);
#pragma unroll
        for (int nt = 0; nt < 4; ++nt) {
            bh8 bf = *(const bh8*)(ldsB + nt * 512 + lane * 8);
            acc[0][nt] = mfma16(af0, bf, acc[0][nt]);
            acc[1][nt] = mfma16(af1, bf, acc[1][nt]);
        }
        __syncthreads();
    }
}

// ---------------- QKV projection ----------------
__global__ __launch_bounds__(256) void k_qkv(unsigned short* __restrict__ ws,
                                             const float* __restrict__ bq,
                                             const float* __restrict__ bk,
                                             const float* __restrict__ bv) {
    const int stile = blockIdx.x;   // 0..31
    const int h     = blockIdx.y;   // 0..15
    const int mat   = blockIdx.z;   // 0=Q 1=K 2=V
    const int row0  = stile * 128;
    const int b     = row0 >> 11;
    const int bh    = b * H_ + h;
    const unsigned short* A  = ws + OFF_XB + (size_t)row0 * D_;
    const unsigned short* Bw = ws + ((mat == 0) ? OFF_WQT : (mat == 1) ? OFF_WKT : OFF_WVT)
                                  + (size_t)h * E_ * D_;
    const float* bias = ((mat == 0) ? bq : (mat == 1) ? bk : bv) + h * E_;

    __shared__ __align__(16) unsigned short lds[12 * 512];
    f32x4 acc[2][4];
#pragma unroll
    for (int i = 0; i < 2; ++i)
#pragma unroll
        for (int j = 0; j < 4; ++j) acc[i][j] = (f32x4){0.f, 0.f, 0.f, 0.f};

    gemm_tile_128x64(A, Bw, lds, lds + 8 * 512, acc);

    const int lane = threadIdx.x & 63, w = threadIdx.x >> 6;
    const int lr = lane & 15, lg = lane >> 4;
    const int srow0 = row0 + w * 32;
    const int sl0   = srow0 & (S_ - 1);
#pragma unroll
    for (int mt = 0; mt < 2; ++mt) {
#pragma unroll
        for (int nt = 0; nt < 4; ++nt) {
            const int e = nt * 16 + lr;
            const float bia = bias[e];
            if (mat == 2) {
                u16x4 pk;
#pragma unroll
                for (int r = 0; r < 4; ++r) pk[r] = f2bf(acc[mt][nt][r] + bia);
                const int sl = sl0 + mt * 16 + lg * 4;
                *(u16x4*)(ws + OFF_VT + ((size_t)(bh * E_ + e)) * S_ + sl) = pk;
            } else {
#pragma unroll
                for (int r = 0; r < 4; ++r) {
                    float v = acc[mt][nt][r] + bia;
                    const int sl = sl0 + mt * 16 + lg * 4 + r;
                    if (mat == 0)   // fold 1/sqrt(64) * log2(e) into Q
                        ws[OFF_Q + ((size_t)bh * S_ + sl) * E_ + e] = f2bf(v * 0.1803368801f);
                    else
                        ws[OFF_K + ((size_t)bh * S_ + sl) * E_ + e] = f2bf(v);
                }
            }
        }
    }
}

// ---------------- flash attention (causal), 64-row q-tiles, 16 rows/wave ----------------
__global__ __launch_bounds__(256, 4) void k_attn(unsigned short* __restrict__ ws) {
    const int qt = 31 - blockIdx.x;  // heavy tiles first (0..31, 64 q rows each)
    const int bh = blockIdx.y;       // 0..31
    const int lane = threadIdx.x & 63, w = threadIdx.x >> 6;
    const int lr = lane & 15, lg = lane >> 4;
    const unsigned short* Qp = ws + OFF_Q  + (size_t)bh * S_ * E_;
    const unsigned short* Kp = ws + OFF_K  + (size_t)bh * S_ * E_;
    const unsigned short* Vp = ws + OFF_VT + (size_t)bh * E_ * S_;
    __shared__ __align__(16) unsigned short ldsK[8 * 512];
    __shared__ __align__(16) unsigned short ldsV[8 * 512];
    __shared__ __align__(16) unsigned short ldsP[4 * 2 * 512];   // per-wave 16x64 P

    const int qbase = qt * 64 + w * 16;   // this wave's 16 q rows
    bh8 qf[2];
#pragma unroll
    for (int kg = 0; kg < 2; ++kg)
        qf[kg] = *(const bh8*)(Qp + (size_t)(qbase + lr) * E_ + kg * 32 + lg * 8);

    f32x4 o[4];
    float m[4], l[4];
#pragma unroll
    for (int i = 0; i < 4; ++i) {
        o[i] = (f32x4){0.f, 0.f, 0.f, 0.f};
        m[i] = -3.0e38f; l[i] = 0.f;
    }

    unsigned short* Pw = ldsP + w * 1024;
    const int nkt = qt + 1;
    for (int kt = 0; kt < nkt; ++kt) {
        const int sk0 = kt * 64;
        // stage K (B-frag order) and V^T (B-frag order): 2 calls/wave each
#pragma unroll
        for (int u = 0; u < 2; ++u) {
            const int blk = w * 2 + u;
            const int ct = blk >> 1, kg = blk & 1;
            gload16(Kp + (size_t)(sk0 + ct * 16 + lr) * E_ + kg * 32 + lg * 8,
                    (unsigned short*)ldsK + blk * 512);
            gload16(Vp + (size_t)(ct * 16 + lr) * S_ + sk0 + kg * 32 + lg * 8,
                    (unsigned short*)ldsV + blk * 512);
        }
        __syncthreads();

        // S = Q K^T (Q pre-scaled by 0.125*log2e -> scores in log2 domain)
        f32x4 sc[4];
#pragma unroll
        for (int ct = 0; ct < 4; ++ct) sc[ct] = (f32x4){0.f, 0.f, 0.f, 0.f};
#pragma unroll
        for (int ct = 0; ct < 4; ++ct)
#pragma unroll
            for (int kg = 0; kg < 2; ++kg) {
                bh8 kf = *(const bh8*)(ldsK + (ct * 2 + kg) * 512 + lane * 8);
                sc[ct] = mfma16(qf[kg], kf, sc[ct]);
            }
        // causal mask: only the diagonal tile needs it (kt == qt)
        if (kt == qt) {
#pragma unroll
            for (int ct = 0; ct < 4; ++ct) {
                const int skc = sk0 + ct * 16 + lr;
#pragma unroll
                for (int r = 0; r < 4; ++r) {
                    const int sq = qbase + lg * 4 + r;
                    if (skc > sq) sc[ct][r] = -3.0e38f;
                }
            }
        }
        // online softmax: row max over 16 lanes
        float mx[4];
#pragma unroll
        for (int r = 0; r < 4; ++r) {
            float v = fmaxf(fmaxf(sc[0][r], sc[1][r]), fmaxf(sc[2][r], sc[3][r]));
            mx[r] = redmax16(v);
        }
        bool need = false;
#pragma unroll
        for (int r = 0; r < 4; ++r) need |= (mx[r] > m[r]);
        if (__any(need)) {   // rescale is identity when mx<=m for all rows
#pragma unroll
            for (int r = 0; r < 4; ++r) {
                const float mn = fmaxf(m[r], mx[r]);
                const float sf = __builtin_amdgcn_exp2f(m[r] - mn);
                m[r] = mn;
                l[r] *= sf;
#pragma unroll
                for (int et = 0; et < 4; ++et) o[et][r] *= sf;
            }
        }
        // P = exp2(S - m), row sums
        float rs[4];
#pragma unroll
        for (int r = 0; r < 4; ++r) rs[r] = 0.f;
#pragma unroll
        for (int ct = 0; ct < 4; ++ct)
#pragma unroll
            for (int r = 0; r < 4; ++r) {
                float p = __builtin_amdgcn_exp2f(sc[ct][r] - m[r]);
                sc[ct][r] = p;
                rs[r] += p;
            }
#pragma unroll
        for (int r = 0; r < 4; ++r) l[r] += redsum16(rs[r]);
        // write P (bf16) into per-wave LDS in A-frag order
#pragma unroll
        for (int ct = 0; ct < 4; ++ct) {
            const int blk = ct >> 1;
            const int lanep = ((ct & 1) * 2 + (lr >> 3)) * 16;
            const int elem = lr & 7;
#pragma unroll
            for (int r = 0; r < 4; ++r)
                Pw[blk * 512 + (lanep + lg * 4 + r) * 8 + elem] = f2bf(sc[ct][r]);
        }
        // O += P V  (wave-local LDS; compiler orders via lgkmcnt)
#pragma unroll
        for (int skg = 0; skg < 2; ++skg) {
            bh8 pf = *(const bh8*)(Pw + skg * 512 + lane * 8);
#pragma unroll
            for (int et = 0; et < 4; ++et) {
                bh8 vf = *(const bh8*)(ldsV + (et * 2 + skg) * 512 + lane * 8);
                o[et] = mfma16(pf, vf, o[et]);
            }
        }
        __syncthreads();   // before restaging K/V
    }
    // epilogue: O/l -> concat layout [B,S,H*64]
    const int b = bh >> 4, hh = bh & 15;
#pragma unroll
    for (int r = 0; r < 4; ++r) {
        const float inv = 1.0f / l[r];
        const int s = qbase + lg * 4 + r;
#pragma unroll
        for (int et = 0; et < 4; ++et)
            ws[OFF_O + ((size_t)(b * S_ + s)) * D_ + hh * E_ + et * 16 + lr] =
                f2bf(o[et][r] * inv);
    }
}

// ---------------- output projection ----------------
__global__ __launch_bounds__(256) void k_oproj(const unsigned short* __restrict__ ws,
                                               const float* __restrict__ bo,
                                               float* __restrict__ out) {
    const int stile = blockIdx.x;   // 0..31
    const int ntile = blockIdx.y;   // 0..15
    const unsigned short* A  = ws + OFF_O   + (size_t)stile * 128 * D_;
    const unsigned short* Bw = ws + OFF_WOT + (size_t)ntile * 64 * D_;
    __shared__ __align__(16) unsigned short lds[12 * 512];
    f32x4 acc[2][4];
#pragma unroll
    for (int i = 0; i < 2; ++i)
#pragma unroll
        for (int j = 0; j < 4; ++j) acc[i][j] = (f32x4){0.f, 0.f, 0.f, 0.f};

    gemm_tile_128x64(A, Bw, (unsigned short*)lds, (unsigned short*)lds + 8 * 512, acc);

    const int lane = threadIdx.x & 63, w = threadIdx.x >> 6;
    const int lr = lane & 15, lg = lane >> 4;
    const int r0 = stile * 128 + w * 32;
#pragma unroll
    for (int mt = 0; mt < 2; ++mt)
#pragma unroll
        for (int nt = 0; nt < 4; ++nt) {
            const int e = ntile * 64 + nt * 16 + lr;
            const float bia = bo[e];
#pragma unroll
            for (int r = 0; r < 4; ++r)
                out[(size_t)(r0 + mt * 16 + lg * 4 + r) * D_ + e] = acc[mt][nt][r] + bia;
        }
}

extern "C" void kernel_launch(void* const* d_in, const int* in_sizes, int n_in,
                              void* d_out, int out_size, void* d_ws, size_t ws_size,
                              hipStream_t stream) {
    const float* x  = (const float*)d_in[0];
    const float* Wq = (const float*)d_in[1];
    const float* bq = (const float*)d_in[2];
    const float* Wk = (const float*)d_in[3];
    const float* bk = (const float*)d_in[4];
    const float* Wv = (const float*)d_in[5];
    const float* bv = (const float*)d_in[6];
    const float* Wo = (const float*)d_in[7];
    const float* bo = (const float*)d_in[8];
    float* out = (float*)d_out;
    unsigned short* ws = (unsigned short*)d_ws;

    k_convert_x<<<dim3((B_ * S_ * D_) / 4 / 256), 256, 0, stream>>>(x, ws);
    k_transpose_w<<<dim3(256, 4), 256, 0, stream>>>(Wq, Wk, Wv, Wo, ws);
    k_qkv<<<dim3(32, 16, 3), 256, 0, stream>>>(ws, bq, bk, bv);
    k_attn<<<dim3(32, 32), 256, 0, stream>>>(ws);
    k_oproj<<<dim3(32, 16), 256, 0, stream>>>(ws, bo, out);
}

// Round 3
// 214.370 us; speedup vs baseline: 1.5596x; 1.0550x over previous
//
#include <hip/hip_runtime.h>
#include <stdint.h>

typedef __attribute__((ext_vector_type(8))) short bh8;       // 8 x bf16 (4 VGPR)
typedef __attribute__((ext_vector_type(4))) float f32x4;
typedef __attribute__((ext_vector_type(4))) unsigned short u16x4;
typedef __attribute__((ext_vector_type(8))) unsigned short u16x8;

#define DEVI static __device__ __forceinline__

constexpr int B_ = 2, S_ = 2048, D_ = 1024, H_ = 16, E_ = 64;

// workspace layout (elements of ushort/bf16)
constexpr size_t OFF_XB  = 0;                              // x as bf16 [B*S, D]
constexpr size_t OFF_WQT = OFF_XB  + (size_t)B_*S_*D_;     // WqT [H, E, D]
constexpr size_t OFF_WKT = OFF_WQT + (size_t)H_*E_*D_;
constexpr size_t OFF_WVT = OFF_WKT + (size_t)H_*E_*D_;
constexpr size_t OFF_WOT = OFF_WVT + (size_t)H_*E_*D_;     // WoT [D, D]
constexpr size_t OFF_Q   = OFF_WOT + (size_t)D_*D_;        // [B*H, S, E]  (pre-scaled by 0.125*log2e)
constexpr size_t OFF_K   = OFF_Q   + (size_t)B_*H_*S_*E_;  // [B*H, S, E]
constexpr size_t OFF_VT  = OFF_K   + (size_t)B_*H_*S_*E_;  // [B*H, E, S]
constexpr size_t OFF_O   = OFF_VT  + (size_t)B_*H_*S_*E_;  // attn out concat [B*S, D]

DEVI unsigned short f2bf(float f) {
    union { float f; unsigned u; } v; v.f = f;
    unsigned u = v.u;
    return (unsigned short)((u + 0x7fffu + ((u >> 16) & 1u)) >> 16);
}

DEVI void gload16(const void* g, void* l) {
    __builtin_amdgcn_global_load_lds(
        (const __attribute__((address_space(1))) unsigned int*)g,
        (__attribute__((address_space(3))) unsigned int*)l, 16, 0, 0);
}

DEVI f32x4 mfma16(bh8 a, bh8 b, f32x4 c) {
    return __builtin_amdgcn_mfma_f32_16x16x32_bf16(a, b, c, 0, 0, 0);
}

DEVI float redmax16(float v) {
    v = fmaxf(v, __shfl_xor(v, 1, 64));
    v = fmaxf(v, __shfl_xor(v, 2, 64));
    v = fmaxf(v, __shfl_xor(v, 4, 64));
    v = fmaxf(v, __shfl_xor(v, 8, 64));
    return v;
}
DEVI float redsum16(float v) {
    v += __shfl_xor(v, 1, 64);
    v += __shfl_xor(v, 2, 64);
    v += __shfl_xor(v, 4, 64);
    v += __shfl_xor(v, 8, 64);
    return v;
}

// ---------------- prep: x -> bf16 ----------------
__global__ __launch_bounds__(256) void k_convert_x(const float* __restrict__ x,
                                                   unsigned short* __restrict__ ws) {
    const int i = blockIdx.x * 256 + threadIdx.x;   // one float4 each; n4 = 1048576
    const float4 v = ((const float4*)x)[i];
    u16x4 o = { f2bf(v.x), f2bf(v.y), f2bf(v.z), f2bf(v.w) };
    *(u16x4*)(ws + OFF_XB + (size_t)i * 4) = o;
}

// ---------------- prep: weights -> bf16, transposed ----------------
__global__ __launch_bounds__(256) void k_transpose_w(const float* __restrict__ Wq,
                                                     const float* __restrict__ Wk,
                                                     const float* __restrict__ Wv,
                                                     const float* __restrict__ Wo,
                                                     unsigned short* __restrict__ ws) {
    const int xi = blockIdx.x;   // 0..255
    const int z  = blockIdx.y;   // 0..3
    const int t  = threadIdx.x;
    __shared__ __align__(16) unsigned short tile[64][72];

    const float* src; unsigned short* dst;
    int inCols, inBase, outBase;
    if (z < 3) {
        src = (z == 0) ? Wq : (z == 1) ? Wk : Wv;
        dst = ws + ((z == 0) ? OFF_WQT : (z == 1) ? OFF_WKT : OFF_WVT);
        inCols = 64;
        inBase = xi * 64 * 64;
        const int h = xi >> 4, dt = xi & 15;
        outBase = h * 65536 + dt * 64;
    } else {
        src = Wo; dst = ws + OFF_WOT;
        inCols = 1024;
        const int et = xi >> 4, dt = xi & 15;
        inBase  = (dt * 64) * 1024 + et * 64;
        outBase = (et * 64) * 1024 + dt * 64;
    }
#pragma unroll
    for (int v = 0; v < 4; ++v) {
        const int flat = v * 256 + t;
        const int i = flat >> 4, j4 = (flat & 15) * 4;
        const float4 val = *(const float4*)(src + inBase + i * inCols + j4);
        tile[i][j4 + 0] = f2bf(val.x);
        tile[i][j4 + 1] = f2bf(val.y);
        tile[i][j4 + 2] = f2bf(val.z);
        tile[i][j4 + 3] = f2bf(val.w);
    }
    __syncthreads();
    const int j = t >> 2, iseg = (t & 3) * 16;
    u16x8 p0, p1;
#pragma unroll
    for (int u = 0; u < 8; ++u) p0[u] = tile[iseg + u][j];
#pragma unroll
    for (int u = 0; u < 8; ++u) p1[u] = tile[iseg + 8 + u][j];
    *(u16x8*)(dst + outBase + (size_t)j * 1024 + iseg)     = p0;
    *(u16x8*)(dst + outBase + (size_t)j * 1024 + iseg + 8) = p1;
}

// ---------------- shared GEMM mainloop: C(128x64) = A(128x1024) * B^T(64x1024)^T ----------------
// Double-buffered: stage tile ks+1 before computing tile ks; single barrier/iter.
// lds must hold 2 * 6144 elements (24 KB).
DEVI void gemm_tile_128x64(const unsigned short* __restrict__ A,
                           const unsigned short* __restrict__ Bw,
                           unsigned short* lds,
                           f32x4 acc[2][4]) {
    const int lane = threadIdx.x & 63;
    const int w    = threadIdx.x >> 6;
    const int lr = lane & 15, lg = lane >> 4;
    const unsigned short* a0 = A  + (size_t)((w * 2 + 0) * 16 + lr) * D_ + lg * 8;
    const unsigned short* a1 = A  + (size_t)((w * 2 + 1) * 16 + lr) * D_ + lg * 8;
    const unsigned short* b0 = Bw + (size_t)(w * 16 + lr) * D_ + lg * 8;
    const int oA0 = (w * 2 + 0) * 512, oA1 = (w * 2 + 1) * 512, oB = 8 * 512 + w * 512;

    auto stage = [&](int ks, int bufi) {
        unsigned short* base = lds + bufi * 6144;
        gload16(a0 + ks * 32, base + oA0);
        gload16(a1 + ks * 32, base + oA1);
        gload16(b0 + ks * 32, base + oB);
    };

    stage(0, 0);
    __syncthreads();
    for (int ks = 0; ks < 32; ++ks) {
        const int cur = ks & 1;
        if (ks + 1 < 32) stage(ks + 1, cur ^ 1);
        const unsigned short* base = lds + cur * 6144;
        bh8 af0 = *(const bh8*)(base + (w * 2 + 0) * 512 + lane * 8);
        bh8 af1 = *(const bh8*)(base + (w * 2 + 1) * 512 + lane * 8);
#pragma unroll
        for (int nt = 0; nt < 4; ++nt) {
            bh8 bf = *(const bh8*)(base + 8 * 512 + nt * 512 + lane * 8);
            acc[0][nt] = mfma16(af0, bf, acc[0][nt]);
            acc[1][nt] = mfma16(af1, bf, acc[1][nt]);
        }
        __syncthreads();   // drains vmcnt: tile ks+1 landed; buffer cur free for reuse
    }
}

// ---------------- QKV projection ----------------
__global__ __launch_bounds__(256) void k_qkv(unsigned short* __restrict__ ws,
                                             const float* __restrict__ bq,
                                             const float* __restrict__ bk,
                                             const float* __restrict__ bv) {
    const int stile = blockIdx.x;   // 0..31
    const int h     = blockIdx.y;   // 0..15
    const int mat   = blockIdx.z;   // 0=Q 1=K 2=V
    const int row0  = stile * 128;
    const int b     = row0 >> 11;
    const int bh    = b * H_ + h;
    const unsigned short* A  = ws + OFF_XB + (size_t)row0 * D_;
    const unsigned short* Bw = ws + ((mat == 0) ? OFF_WQT : (mat == 1) ? OFF_WKT : OFF_WVT)
                                  + (size_t)h * E_ * D_;
    const float* bias = ((mat == 0) ? bq : (mat == 1) ? bk : bv) + h * E_;

    __shared__ __align__(16) unsigned short lds[2 * 6144];
    f32x4 acc[2][4];
#pragma unroll
    for (int i = 0; i < 2; ++i)
#pragma unroll
        for (int j = 0; j < 4; ++j) acc[i][j] = (f32x4){0.f, 0.f, 0.f, 0.f};

    gemm_tile_128x64(A, Bw, lds, acc);

    const int lane = threadIdx.x & 63, w = threadIdx.x >> 6;
    const int lr = lane & 15, lg = lane >> 4;
    const int srow0 = row0 + w * 32;
    const int sl0   = srow0 & (S_ - 1);
#pragma unroll
    for (int mt = 0; mt < 2; ++mt) {
#pragma unroll
        for (int nt = 0; nt < 4; ++nt) {
            const int e = nt * 16 + lr;
            const float bia = bias[e];
            if (mat == 2) {
                u16x4 pk;
#pragma unroll
                for (int r = 0; r < 4; ++r) pk[r] = f2bf(acc[mt][nt][r] + bia);
                const int sl = sl0 + mt * 16 + lg * 4;
                *(u16x4*)(ws + OFF_VT + ((size_t)(bh * E_ + e)) * S_ + sl) = pk;
            } else {
#pragma unroll
                for (int r = 0; r < 4; ++r) {
                    float v = acc[mt][nt][r] + bia;
                    const int sl = sl0 + mt * 16 + lg * 4 + r;
                    if (mat == 0)   // fold 1/sqrt(64) * log2(e) into Q
                        ws[OFF_Q + ((size_t)bh * S_ + sl) * E_ + e] = f2bf(v * 0.1803368801f);
                    else
                        ws[OFF_K + ((size_t)bh * S_ + sl) * E_ + e] = f2bf(v);
                }
            }
        }
    }
}

// ---------------- flash attention (causal), 64-row q-tiles, 16 rows/wave ----------------
// Double-buffered K/V staging: prefetch tile kt+1 before computing kt.
__global__ __launch_bounds__(256, 4) void k_attn(unsigned short* __restrict__ ws) {
    const int qt = 31 - blockIdx.x;  // heavy tiles first (0..31, 64 q rows each)
    const int bh = blockIdx.y;       // 0..31
    const int lane = threadIdx.x & 63, w = threadIdx.x >> 6;
    const int lr = lane & 15, lg = lane >> 4;
    const unsigned short* Qp = ws + OFF_Q  + (size_t)bh * S_ * E_;
    const unsigned short* Kp = ws + OFF_K  + (size_t)bh * S_ * E_;
    const unsigned short* Vp = ws + OFF_VT + (size_t)bh * E_ * S_;
    __shared__ __align__(16) unsigned short ldsK[2][8 * 512];
    __shared__ __align__(16) unsigned short ldsV[2][8 * 512];
    __shared__ __align__(16) unsigned short ldsP[4 * 1024];   // per-wave 16x64 P

    const int qbase = qt * 64 + w * 16;   // this wave's 16 q rows
    bh8 qf[2];
#pragma unroll
    for (int kg = 0; kg < 2; ++kg)
        qf[kg] = *(const bh8*)(Qp + (size_t)(qbase + lr) * E_ + kg * 32 + lg * 8);

    f32x4 o[4];
    float m[4], l[4];
#pragma unroll
    for (int i = 0; i < 4; ++i) {
        o[i] = (f32x4){0.f, 0.f, 0.f, 0.f};
        m[i] = -3.0e38f; l[i] = 0.f;
    }

    auto stage = [&](int kt, int bufi) {
        const int sk0 = kt * 64;
#pragma unroll
        for (int u = 0; u < 2; ++u) {
            const int blk = w * 2 + u;
            const int ct = blk >> 1, kg = blk & 1;
            gload16(Kp + (size_t)(sk0 + ct * 16 + lr) * E_ + kg * 32 + lg * 8,
                    &ldsK[bufi][blk * 512]);
            gload16(Vp + (size_t)(ct * 16 + lr) * S_ + sk0 + kg * 32 + lg * 8,
                    &ldsV[bufi][blk * 512]);
        }
    };

    unsigned short* Pw = ldsP + w * 1024;
    const int nkt = qt + 1;

    stage(0, 0);
    __syncthreads();

    for (int kt = 0; kt < nkt; ++kt) {
        const int cur = kt & 1;
        if (kt + 1 < nkt) stage(kt + 1, cur ^ 1);   // prefetch next tile
        const int sk0 = kt * 64;
        const unsigned short* Kc = ldsK[cur];
        const unsigned short* Vc = ldsV[cur];

        // S = Q K^T (Q pre-scaled by 0.125*log2e -> scores in log2 domain)
        f32x4 sc[4];
#pragma unroll
        for (int ct = 0; ct < 4; ++ct) sc[ct] = (f32x4){0.f, 0.f, 0.f, 0.f};
#pragma unroll
        for (int ct = 0; ct < 4; ++ct)
#pragma unroll
            for (int kg = 0; kg < 2; ++kg) {
                bh8 kf = *(const bh8*)(Kc + (ct * 2 + kg) * 512 + lane * 8);
                sc[ct] = mfma16(qf[kg], kf, sc[ct]);
            }
        // causal mask: only the diagonal tile needs it (kt == qt)
        if (kt == qt) {
#pragma unroll
            for (int ct = 0; ct < 4; ++ct) {
                const int skc = sk0 + ct * 16 + lr;
#pragma unroll
                for (int r = 0; r < 4; ++r) {
                    const int sq = qbase + lg * 4 + r;
                    if (skc > sq) sc[ct][r] = -3.0e38f;
                }
            }
        }
        // online softmax: row max over 16 lanes
        float mx[4];
#pragma unroll
        for (int r = 0; r < 4; ++r) {
            float v = fmaxf(fmaxf(sc[0][r], sc[1][r]), fmaxf(sc[2][r], sc[3][r]));
            mx[r] = redmax16(v);
        }
        bool need = false;
#pragma unroll
        for (int r = 0; r < 4; ++r) need |= (mx[r] > m[r]);
        if (__any(need)) {   // rescale is identity when mx<=m for all rows
#pragma unroll
            for (int r = 0; r < 4; ++r) {
                const float mn = fmaxf(m[r], mx[r]);
                const float sf = __builtin_amdgcn_exp2f(m[r] - mn);
                m[r] = mn;
                l[r] *= sf;
#pragma unroll
                for (int et = 0; et < 4; ++et) o[et][r] *= sf;
            }
        }
        // P = exp2(S - m), row sums
        float rs[4];
#pragma unroll
        for (int r = 0; r < 4; ++r) rs[r] = 0.f;
#pragma unroll
        for (int ct = 0; ct < 4; ++ct)
#pragma unroll
            for (int r = 0; r < 4; ++r) {
                float p = __builtin_amdgcn_exp2f(sc[ct][r] - m[r]);
                sc[ct][r] = p;
                rs[r] += p;
            }
#pragma unroll
        for (int r = 0; r < 4; ++r) l[r] += redsum16(rs[r]);
        // write P (bf16) into per-wave LDS in A-frag order
#pragma unroll
        for (int ct = 0; ct < 4; ++ct) {
            const int blk = ct >> 1;
            const int lanep = ((ct & 1) * 2 + (lr >> 3)) * 16;
            const int elem = lr & 7;
#pragma unroll
            for (int r = 0; r < 4; ++r)
                Pw[blk * 512 + (lanep + lg * 4 + r) * 8 + elem] = f2bf(sc[ct][r]);
        }
        // O += P V  (wave-local LDS; compiler orders via lgkmcnt)
#pragma unroll
        for (int skg = 0; skg < 2; ++skg) {
            bh8 pf = *(const bh8*)(Pw + skg * 512 + lane * 8);
#pragma unroll
            for (int et = 0; et < 4; ++et) {
                bh8 vf = *(const bh8*)(Vc + (et * 2 + skg) * 512 + lane * 8);
                o[et] = mfma16(pf, vf, o[et]);
            }
        }
        __syncthreads();   // drains vmcnt: prefetched tile landed; cur buffer reusable
    }
    // epilogue: O/l -> concat layout [B,S,H*64]
    const int b = bh >> 4, hh = bh & 15;
#pragma unroll
    for (int r = 0; r < 4; ++r) {
        const float inv = 1.0f / l[r];
        const int s = qbase + lg * 4 + r;
#pragma unroll
        for (int et = 0; et < 4; ++et)
            ws[OFF_O + ((size_t)(b * S_ + s)) * D_ + hh * E_ + et * 16 + lr] =
                f2bf(o[et][r] * inv);
    }
}

// ---------------- output projection ----------------
__global__ __launch_bounds__(256) void k_oproj(const unsigned short* __restrict__ ws,
                                               const float* __restrict__ bo,
                                               float* __restrict__ out) {
    const int stile = blockIdx.x;   // 0..31
    const int ntile = blockIdx.y;   // 0..15
    const unsigned short* A  = ws + OFF_O   + (size_t)stile * 128 * D_;
    const unsigned short* Bw = ws + OFF_WOT + (size_t)ntile * 64 * D_;
    __shared__ __align__(16) unsigned short lds[2 * 6144];
    f32x4 acc[2][4];
#pragma unroll
    for (int i = 0; i < 2; ++i)
#pragma unroll
        for (int j = 0; j < 4; ++j) acc[i][j] = (f32x4){0.f, 0.f, 0.f, 0.f};

    gemm_tile_128x64(A, Bw, lds, acc);

    const int lane = threadIdx.x & 63, w = threadIdx.x >> 6;
    const int lr = lane & 15, lg = lane >> 4;
    const int r0 = stile * 128 + w * 32;
#pragma unroll
    for (int mt = 0; mt < 2; ++mt)
#pragma unroll
        for (int nt = 0; nt < 4; ++nt) {
            const int e = ntile * 64 + nt * 16 + lr;
            const float bia = bo[e];
#pragma unroll
            for (int r = 0; r < 4; ++r)
                out[(size_t)(r0 + mt * 16 + lg * 4 + r) * D_ + e] = acc[mt][nt][r] + bia;
        }
}

extern "C" void kernel_launch(void* const* d_in, const int* in_sizes, int n_in,
                              void* d_out, int out_size, void* d_ws, size_t ws_size,
                              hipStream_t stream) {
    const float* x  = (const float*)d_in[0];
    const float* Wq = (const float*)d_in[1];
    const float* bq = (const float*)d_in[2];
    const float* Wk = (const float*)d_in[3];
    const float* bk = (const float*)d_in[4];
    const float* Wv = (const float*)d_in[5];
    const float* bv = (const float*)d_in[6];
    const float* Wo = (const float*)d_in[7];
    const float* bo = (const float*)d_in[8];
    float* out = (float*)d_out;
    unsigned short* ws = (unsigned short*)d_ws;

    k_convert_x<<<dim3((B_ * S_ * D_) / 4 / 256), 256, 0, stream>>>(x, ws);
    k_transpose_w<<<dim3(256, 4), 256, 0, stream>>>(Wq, Wk, Wv, Wo, ws);
    k_qkv<<<dim3(32, 16, 3), 256, 0, stream>>>(ws, bq, bk, bv);
    k_attn<<<dim3(32, 32), 256, 0, stream>>>(ws);
    k_oproj<<<dim3(32, 16), 256, 0, stream>>>(ws, bo, out);
}